// Round 1
// baseline (326.600 us; speedup 1.0000x reference)
//
#include <hip/hip_runtime.h>
#include <cstdint>
#include <cstddef>

#define B_ 4
#define T_ 2048
#define C_ 768
#define H_ 16
#define D_ 48
#define M_ (B_*T_)      // 8192
#define N3_ (3*C_)      // 2304

typedef unsigned short u16;
typedef __attribute__((ext_vector_type(8))) short bf16x8;
typedef __attribute__((ext_vector_type(4))) float f32x4;
typedef __attribute__((ext_vector_type(4))) unsigned int u32x4;
typedef __attribute__((ext_vector_type(4))) unsigned short u16x4;

__device__ __forceinline__ u16 f2b(float f){
  union { float f; unsigned u; } x; x.f = f;
  unsigned u = x.u;
  return (u16)((u + 0x7FFFu + ((u >> 16) & 1u)) >> 16);
}

// Swizzled LDS fragment load. All LDS tiles use 128-byte row pitch.
// Physical byte = row*128 + (col_byte ^ ((row&7)<<4)).
__device__ __forceinline__ bf16x8 ld_frag(const u16* lds, int row, int kbyte){
  const char* p = (const char*)lds + (row << 7) + (kbyte ^ ((row & 7) << 4));
  return *(const bf16x8*)p;
}

// ---------------- fp32 -> bf16 convert (vectorized x4) ----------------
__global__ void k_cvt(const float* __restrict__ in, u16* __restrict__ out, int n4){
  int i = blockIdx.x * blockDim.x + threadIdx.x;
  if (i >= n4) return;
  f32x4 v = *(const f32x4*)(in + 4*(size_t)i);
  u16x4 o;
  o.x = f2b(v.x); o.y = f2b(v.y); o.z = f2b(v.z); o.w = f2b(v.w);
  *(u16x4*)(out + 4*(size_t)i) = o;
}

// ---------------- fp32 [R][Cn] -> bf16 transposed [Cn][R] ----------------
__global__ void k_tpose(const float* __restrict__ in, u16* __restrict__ out, int R, int Cn){
  __shared__ float tile[32][33];
  int tx = threadIdx.x & 31, ty = threadIdx.x >> 5;  // ty 0..7
  int c  = blockIdx.x * 32 + tx;
  int rb = blockIdx.y * 32;
  #pragma unroll
  for (int r0 = 0; r0 < 32; r0 += 8)
    tile[ty + r0][tx] = in[(size_t)(rb + ty + r0) * Cn + c];
  __syncthreads();
  int oc = rb + tx;
  int cb = blockIdx.x * 32;
  #pragma unroll
  for (int r0 = 0; r0 < 32; r0 += 8)
    out[(size_t)(cb + ty + r0) * R + oc] = f2b(tile[tx][ty + r0]);
}

// ---------------- bf16 GEMM: C[m][n] = sum_k A[m][k]*Bt[n][k] ----------------
// 128x128 tile, BK=64, 4 waves (2x2), each wave 4x4 frags of 16x16x32 MFMA.
template<bool OUT_BF16, bool ADD_BIAS>
__launch_bounds__(256)
__global__ void k_gemm(const u16* __restrict__ A, const u16* __restrict__ Bt,
                       void* __restrict__ Cout, const float* __restrict__ bias,
                       int Ndim, int Kdim){
  __shared__ u16 lA[128*64];
  __shared__ u16 lB[128*64];
  const int tid = threadIdx.x, lane = tid & 63, w = tid >> 6;
  const int m0 = blockIdx.x * 128, n0 = blockIdx.y * 128;
  const int wr = (w >> 1) * 64, wc = (w & 1) * 64;
  const f32x4 fzero = {0.f, 0.f, 0.f, 0.f};
  f32x4 acc[4][4];
  #pragma unroll
  for (int i = 0; i < 4; ++i)
    #pragma unroll
    for (int j = 0; j < 4; ++j) acc[i][j] = fzero;

  for (int k0 = 0; k0 < Kdim; k0 += 64){
    __syncthreads();
    // stage both tiles: 1024 chunks of 16B each, linear LDS dest, pre-swizzled source col
    for (int c = tid; c < 1024; c += 256){
      int row  = c >> 3;
      int cb   = (c & 7) << 4;
      int pcol = cb ^ ((row & 7) << 4);
      *(u32x4*)((char*)lA + (c << 4)) =
        *(const u32x4*)((const char*)(A + (size_t)(m0 + row) * Kdim + k0) + pcol);
      *(u32x4*)((char*)lB + (c << 4)) =
        *(const u32x4*)((const char*)(Bt + (size_t)(n0 + row) * Kdim + k0) + pcol);
    }
    __syncthreads();
    #pragma unroll
    for (int kk = 0; kk < 2; ++kk){
      int kbyte = (kk << 6) + ((lane >> 4) << 4);
      bf16x8 af[4], bfv[4];
      #pragma unroll
      for (int i = 0; i < 4; ++i){
        af[i]  = ld_frag(lA, wr + i*16 + (lane & 15), kbyte);
        bfv[i] = ld_frag(lB, wc + i*16 + (lane & 15), kbyte);
      }
      #pragma unroll
      for (int i = 0; i < 4; ++i)
        #pragma unroll
        for (int j = 0; j < 4; ++j)
          acc[i][j] = __builtin_amdgcn_mfma_f32_16x16x32_bf16(af[i], bfv[j], acc[i][j], 0, 0, 0);
    }
  }
  // epilogue: C row = (lane>>4)*4 + r, col = lane&15 (m89/m91 layout)
  #pragma unroll
  for (int i = 0; i < 4; ++i){
    int rbase = m0 + wr + i*16 + ((lane >> 4) << 2);
    #pragma unroll
    for (int j = 0; j < 4; ++j){
      int col = n0 + wc + j*16 + (lane & 15);
      float bv = ADD_BIAS ? bias[col] : 0.f;
      #pragma unroll
      for (int r = 0; r < 4; ++r){
        float v = acc[i][j][r] + bv;
        if (OUT_BF16) ((u16*)Cout)[(size_t)(rbase + r) * Ndim + col] = f2b(v);
        else          ((float*)Cout)[(size_t)(rbase + r) * Ndim + col] = v;
      }
    }
  }
}

// ---------------- V transpose: vt[bh][d][t] from qkv ----------------
__global__ void k_vt(const u16* __restrict__ qkv, u16* __restrict__ vt){
  __shared__ u16 tl[64][50];
  int t0 = blockIdx.x * 64;
  int bh = blockIdx.y; int b = bh >> 4, h = bh & 15;
  int tid = threadIdx.x;
  for (int i = tid; i < 64*48; i += 256){
    int tt = i / 48, d = i % 48;
    tl[tt][d] = qkv[(size_t)(b*T_ + t0 + tt) * N3_ + 2*C_ + h*D_ + d];
  }
  __syncthreads();
  for (int i = tid; i < 48*64; i += 256){
    int d = i >> 6, tt = i & 63;
    vt[(size_t)(bh*D_ + d) * T_ + t0 + tt] = tl[tt][d];
  }
}

// ---------------- causal flash attention ----------------
// grid: (T/64 q-tiles, B*H). block = 256 (4 waves); wave w owns q rows [w*16, w*16+16).
__launch_bounds__(256)
__global__ void k_attn(const u16* __restrict__ qkv, const u16* __restrict__ vt,
                       u16* __restrict__ ao){
  __shared__ u16 lQ[64*64];
  __shared__ u16 lK[64*64];
  __shared__ u16 lV[48*64];
  __shared__ u16 lP[4][16*64];
  const int qb = blockIdx.x, bh = blockIdx.y;
  const int b = bh >> 4, h = bh & 15;
  const int tid = threadIdx.x, lane = tid & 63, w = tid >> 6;
  const f32x4 fzero = {0.f, 0.f, 0.f, 0.f};
  const u32x4 uzero = {0u, 0u, 0u, 0u};

  // zero the d-pad (logical cols 96..127 bytes) of lQ and lK once
  {
    int c = tid;              // exactly 256 chunks
    int row  = (c >> 1) & 63;
    int cb   = 96 + ((c & 1) << 4);
    u16* base = (c >> 7) ? lK : lQ;
    *(u32x4*)((char*)base + (row << 7) + (cb ^ ((row & 7) << 4))) = uzero;
  }
  // stage Q: 64 rows x 96B
  for (int c = tid; c < 384; c += 256){
    int row = c / 6, cb = (c % 6) << 4;
    const char* g = (const char*)(qkv + (size_t)(b*T_ + qb*64 + row) * N3_ + h*D_) + cb;
    *(u32x4*)((char*)lQ + (row << 7) + (cb ^ ((row & 7) << 4))) = *(const u32x4*)g;
  }
  __syncthreads();
  bf16x8 aq[2];
  #pragma unroll
  for (int kk = 0; kk < 2; ++kk)
    aq[kk] = ld_frag(lQ, w*16 + (lane & 15), (kk << 6) + ((lane >> 4) << 4));

  float mrun[4], lrun[4];
  f32x4 oacc[3];
  #pragma unroll
  for (int r = 0; r < 4; ++r){ mrun[r] = -1e30f; lrun[r] = 0.f; }
  #pragma unroll
  for (int nf = 0; nf < 3; ++nf) oacc[nf] = fzero;

  const float scale = 0.14433756729740643f;  // 48^-0.5

  for (int kb = 0; kb <= qb; ++kb){
    __syncthreads();   // prior iteration's LDS reads complete before restage
    for (int c = tid; c < 384; c += 256){
      int row = c / 6, cb = (c % 6) << 4;
      const char* g = (const char*)(qkv + (size_t)(b*T_ + kb*64 + row) * N3_ + C_ + h*D_) + cb;
      *(u32x4*)((char*)lK + (row << 7) + (cb ^ ((row & 7) << 4))) = *(const u32x4*)g;
    }
    for (int c = tid; c < 384; c += 256){
      int d = c >> 3, cb = (c & 7) << 4;
      const char* g = (const char*)(vt + (size_t)(bh*D_ + d) * T_ + kb*64) + cb;
      *(u32x4*)((char*)lV + (d << 7) + (cb ^ ((d & 7) << 4))) = *(const u32x4*)g;
    }
    __syncthreads();

    // S = Q K^T  (S[q][key]; q = (lane>>4)*4+r, key = nf*16 + (lane&15))
    f32x4 s[4];
    #pragma unroll
    for (int nf = 0; nf < 4; ++nf) s[nf] = fzero;
    #pragma unroll
    for (int kk = 0; kk < 2; ++kk){
      int kbyte = (kk << 6) + ((lane >> 4) << 4);
      #pragma unroll
      for (int nf = 0; nf < 4; ++nf){
        bf16x8 bk = ld_frag(lK, nf*16 + (lane & 15), kbyte);
        s[nf] = __builtin_amdgcn_mfma_f32_16x16x32_bf16(aq[kk], bk, s[nf], 0, 0, 0);
      }
    }

    // online softmax
    int qg0 = qb*64 + w*16 + ((lane >> 4) << 2);
    int kg0 = kb*64 + (lane & 15);
    float p[4][4], rmax[4];
    #pragma unroll
    for (int r = 0; r < 4; ++r){
      float mx = -1e30f;
      #pragma unroll
      for (int nf = 0; nf < 4; ++nf){
        float v = s[nf][r] * scale;
        v = (kg0 + nf*16 <= qg0 + r) ? v : -1e30f;
        p[nf][r] = v;
        mx = fmaxf(mx, v);
      }
      rmax[r] = mx;
    }
    #pragma unroll
    for (int off = 8; off; off >>= 1)
      #pragma unroll
      for (int r = 0; r < 4; ++r)
        rmax[r] = fmaxf(rmax[r], __shfl_xor(rmax[r], off));
    float corr[4], rsum[4];
    #pragma unroll
    for (int r = 0; r < 4; ++r){
      float mn = fmaxf(mrun[r], rmax[r]);
      corr[r] = __expf(mrun[r] - mn);
      mrun[r] = mn;
      float sum = 0.f;
      #pragma unroll
      for (int nf = 0; nf < 4; ++nf){
        float e = __expf(p[nf][r] - mn);
        p[nf][r] = e;
        sum += e;
      }
      rsum[r] = sum;
    }
    #pragma unroll
    for (int off = 8; off; off >>= 1)
      #pragma unroll
      for (int r = 0; r < 4; ++r)
        rsum[r] += __shfl_xor(rsum[r], off);
    #pragma unroll
    for (int r = 0; r < 4; ++r)
      lrun[r] = lrun[r] * corr[r] + rsum[r];
    #pragma unroll
    for (int nf = 0; nf < 3; ++nf)
      #pragma unroll
      for (int r = 0; r < 4; ++r)
        oacc[nf][r] *= corr[r];

    // write P (bf16) to this wave's private swizzled LDS tile
    u16* myP = &lP[w][0];
    #pragma unroll
    for (int nf = 0; nf < 4; ++nf)
      #pragma unroll
      for (int r = 0; r < 4; ++r){
        int prow = ((lane >> 4) << 2) + r;
        int pcb  = (nf*16 + (lane & 15)) << 1;
        *(u16*)((char*)myP + (prow << 7) + (pcb ^ ((prow & 7) << 4))) = f2b(p[nf][r]);
      }

    // O += P V   (A = P[q][key], B^T = Vt[d][key])
    #pragma unroll
    for (int kk = 0; kk < 2; ++kk){
      int kbyte = (kk << 6) + ((lane >> 4) << 4);
      bf16x8 pa = ld_frag(myP, lane & 15, kbyte);
      #pragma unroll
      for (int nf = 0; nf < 3; ++nf){
        bf16x8 bv = ld_frag(lV, nf*16 + (lane & 15), kbyte);
        oacc[nf] = __builtin_amdgcn_mfma_f32_16x16x32_bf16(pa, bv, oacc[nf], 0, 0, 0);
      }
    }
  }

  // epilogue: divide by running sum, store bf16 [B*T][C]
  #pragma unroll
  for (int r = 0; r < 4; ++r){
    float inv = 1.f / lrun[r];
    int t = qb*64 + w*16 + ((lane >> 4) << 2) + r;
    #pragma unroll
    for (int nf = 0; nf < 3; ++nf){
      int col = h*D_ + nf*16 + (lane & 15);
      ao[(size_t)(b*T_ + t) * C_ + col] = f2b(oacc[nf][r] * inv);
    }
  }
}

extern "C" void kernel_launch(void* const* d_in, const int* in_sizes, int n_in,
                              void* d_out, int out_size, void* d_ws, size_t ws_size,
                              hipStream_t stream){
  if (n_in < 4) return;
  const float* x      = (const float*)d_in[0];
  const float* W_attn = (const float*)d_in[1];
  const float* W_proj = (const float*)d_in[2];
  const float* b_proj = (const float*)d_in[3];

  char* ws = (char*)d_ws;
  size_t off = 0;
  auto alloc = [&](size_t bytes)->void*{
    void* p = ws + off; off += (bytes + 255) & ~(size_t)255; return p;
  };
  u16* xb   = (u16*)alloc((size_t)M_ * C_  * 2);
  u16* wabT = (u16*)alloc((size_t)N3_ * C_ * 2);
  u16* wpbT = (u16*)alloc((size_t)C_ * C_  * 2);
  u16* qkv  = (u16*)alloc((size_t)M_ * N3_ * 2);
  u16* vt   = (u16*)alloc((size_t)B_ * H_ * D_ * T_ * 2);
  u16* ao   = (u16*)alloc((size_t)M_ * C_  * 2);
  if (off > ws_size) return;  // workspace too small — bail cleanly

  k_cvt<<<dim3((M_*C_/4 + 255)/256), dim3(256), 0, stream>>>(x, xb, M_*C_/4);
  k_tpose<<<dim3(N3_/32, C_/32), dim3(256), 0, stream>>>(W_attn, wabT, C_, N3_);
  k_tpose<<<dim3(C_/32,  C_/32), dim3(256), 0, stream>>>(W_proj, wpbT, C_, C_);
  k_gemm<true,false><<<dim3(M_/128, N3_/128), dim3(256), 0, stream>>>(
      xb, wabT, (void*)qkv, (const float*)nullptr, N3_, C_);
  k_vt<<<dim3(T_/64, B_*H_), dim3(256), 0, stream>>>(qkv, vt);
  k_attn<<<dim3(T_/64, B_*H_), dim3(256), 0, stream>>>(qkv, vt, ao);
  k_gemm<false,true><<<dim3(M_/128, C_/128), dim3(256), 0, stream>>>(
      ao, wpbT, d_out, b_proj, C_, C_);
}